// Round 7
// baseline (127744.043 us; speedup 1.0000x reference)
//
#include <hip/hip_runtime.h>
#include <math.h>

#define NB    2048
#define FIN   32
#define HH    512
#define G4    2048           // 4*H
#define BNE   64
#define OUTD  8
#define SEQL  128
#define LOOK  32
#define TOT   (SEQL + LOOK)
#define TB    8              // samples per workgroup
#define NTHR  1024

__device__ __forceinline__ float sigf(float v) { return 1.0f / (1.0f + expf(-v)); }

// 2 samples (hv.x, hv.y) x 2 units (w.x, w.y): 4 FMAs into A[0..1]
#define GMAC2(A, W, HV)                                                  \
  { A[0].x = fmaf((W).x, (HV).x, A[0].x); A[0].y = fmaf((W).y, (HV).x, A[0].y); \
    A[1].x = fmaf((W).x, (HV).y, A[1].x); A[1].y = fmaf((W).y, (HV).y, A[1].y); }

__global__ __launch_bounds__(NTHR, 4)
void fused_rnn(const float* __restrict__ x,
               const float* __restrict__ Wih0, const float* __restrict__ Whh0,
               const float* __restrict__ bih0, const float* __restrict__ bhh0,
               const float* __restrict__ Wih1, const float* __restrict__ Whh1,
               const float* __restrict__ bih1, const float* __restrict__ bhh1,
               const float* __restrict__ We,   const float* __restrict__ be,
               const float* __restrict__ Wd,   const float* __restrict__ bd,
               const float* __restrict__ Wf,   const float* __restrict__ bf,
               float* __restrict__ out)
{
  // states [unit][sample]: fixed-k access is a wave-uniform broadcast
  __shared__ float sh0[HH][TB], sc0[HH][TB], sh1[HH][TB], sc1[HH][TB];  // 64 KB
  __shared__ float tq[2][BNE][TB];   // trits as float, 4 KB
  __shared__ float sx[FIN][TB];      // staged x_t, 1 KB
  __shared__ float sout[TB][OUTD];   // dense output (AR feedback)

  const int t  = threadIdx.x;          // 0..1023
  const int b0 = blockIdx.x * TB;

  for (int i = t; i < HH * TB; i += NTHR) {
    (&sh0[0][0])[i] = 0.f; (&sc0[0][0])[i] = 0.f;
    (&sh1[0][0])[i] = 0.f; (&sc1[0][0])[i] = 0.f;
  }

  // ---- matmul mapping: thread owns units {2q,2q+1} (all 4 gates), samples {s2, s2+1} ----
  const int q   = t & 255;             // unit-pair index
  const int sh2 = t >> 8;              // sample-pair index 0..3
  const int s2  = 2 * sh2;
  const int u0  = 2 * q;
  float2 bg0[4], bg1[4];
#pragma unroll
  for (int m = 0; m < 4; m++) {
    const int c = m * HH + u0;
    bg0[m] = make_float2(bih0[c] + bhh0[c], bih0[c + 1] + bhh0[c + 1]);
    bg1[m] = make_float2(bih1[c] + bhh1[c], bih1[c + 1] + bhh1[c + 1]);
  }

  // ---- encoder mapping: (ae, n, sample) — one chain per thread ----
  const int ae = t >> 9, sE = (t >> 6) & 7, n = t & 63;

  // ---- decoder mapping: col t of Wd (h-part if t<512, else c-part) ----
  const float bdc = bd[t];

  const double Athr = 0.5493061443340549;  // atanh(0.5)

  for (int step = 0; step < TOT; ++step) {
    __syncthreads();

    // ================= A: AE encoders (fp64, exact chain order, 1 sample/thread) ====
    {
      const float* Sh = ae ? &sh1[0][0] : &sh0[0][0];
      const float* Sc = ae ? &sc1[0][0] : &sc0[0][0];
      double a0 = (double)be[n];
      const float* weh = We + n;
#pragma unroll 4
      for (int k = 0; k < HH; k++)
        a0 = fma((double)Sh[k * TB + sE], (double)weh[(size_t)k * BNE], a0);
      const float* wec = We + (size_t)HH * BNE + n;
#pragma unroll 4
      for (int k = 0; k < HH; k++)
        a0 = fma((double)Sc[k * TB + sE], (double)wec[(size_t)k * BNE], a0);
      tq[ae][n][sE] = (a0 > Athr) ? 1.f : ((a0 < -Athr) ? -1.f : 0.f);
    }
    __syncthreads();

    // ================= B: AE decode (1 col/thread, 8 samples, both AEs) + stage x_t ==
    {
      float d0[TB], d1[TB];
#pragma unroll
      for (int s = 0; s < TB; s++) { d0[s] = bdc; d1[s] = bdc; }
      const float* wd = Wd + t;
      float w = wd[0];
#pragma unroll 4
      for (int j = 0; j < BNE - 1; j++) {
        const float wn = wd[(size_t)(j + 1) * (2 * HH)];
        const float4 qA0 = *(const float4*)&tq[0][j][0];
        const float4 qB0 = *(const float4*)&tq[0][j][4];
        const float4 qA1 = *(const float4*)&tq[1][j][0];
        const float4 qB1 = *(const float4*)&tq[1][j][4];
        d0[0] = fmaf(qA0.x, w, d0[0]); d0[1] = fmaf(qA0.y, w, d0[1]);
        d0[2] = fmaf(qA0.z, w, d0[2]); d0[3] = fmaf(qA0.w, w, d0[3]);
        d0[4] = fmaf(qB0.x, w, d0[4]); d0[5] = fmaf(qB0.y, w, d0[5]);
        d0[6] = fmaf(qB0.z, w, d0[6]); d0[7] = fmaf(qB0.w, w, d0[7]);
        d1[0] = fmaf(qA1.x, w, d1[0]); d1[1] = fmaf(qA1.y, w, d1[1]);
        d1[2] = fmaf(qA1.z, w, d1[2]); d1[3] = fmaf(qA1.w, w, d1[3]);
        d1[4] = fmaf(qB1.x, w, d1[4]); d1[5] = fmaf(qB1.y, w, d1[5]);
        d1[6] = fmaf(qB1.z, w, d1[6]); d1[7] = fmaf(qB1.w, w, d1[7]);
        w = wn;
      }
      { // j = BNE-1
        const int j = BNE - 1;
        const float4 qA0 = *(const float4*)&tq[0][j][0];
        const float4 qB0 = *(const float4*)&tq[0][j][4];
        const float4 qA1 = *(const float4*)&tq[1][j][0];
        const float4 qB1 = *(const float4*)&tq[1][j][4];
        d0[0] = fmaf(qA0.x, w, d0[0]); d0[1] = fmaf(qA0.y, w, d0[1]);
        d0[2] = fmaf(qA0.z, w, d0[2]); d0[3] = fmaf(qA0.w, w, d0[3]);
        d0[4] = fmaf(qB0.x, w, d0[4]); d0[5] = fmaf(qB0.y, w, d0[5]);
        d0[6] = fmaf(qB0.z, w, d0[6]); d0[7] = fmaf(qB0.w, w, d0[7]);
        d1[0] = fmaf(qA1.x, w, d1[0]); d1[1] = fmaf(qA1.y, w, d1[1]);
        d1[2] = fmaf(qA1.z, w, d1[2]); d1[3] = fmaf(qA1.w, w, d1[3]);
        d1[4] = fmaf(qB1.x, w, d1[4]); d1[5] = fmaf(qB1.y, w, d1[5]);
        d1[6] = fmaf(qB1.z, w, d1[6]); d1[7] = fmaf(qB1.w, w, d1[7]);
      }
      if (t < HH) {              // h-unit t
        *(float4*)&sh0[t][0] = make_float4(d0[0], d0[1], d0[2], d0[3]);
        *(float4*)&sh0[t][4] = make_float4(d0[4], d0[5], d0[6], d0[7]);
        *(float4*)&sh1[t][0] = make_float4(d1[0], d1[1], d1[2], d1[3]);
        *(float4*)&sh1[t][4] = make_float4(d1[4], d1[5], d1[6], d1[7]);
      } else {                   // c-unit t-HH
        const int u = t - HH;
        *(float4*)&sc0[u][0] = make_float4(d0[0], d0[1], d0[2], d0[3]);
        *(float4*)&sc0[u][4] = make_float4(d0[4], d0[5], d0[6], d0[7]);
        *(float4*)&sc1[u][0] = make_float4(d1[0], d1[1], d1[2], d1[3]);
        *(float4*)&sc1[u][4] = make_float4(d1[4], d1[5], d1[6], d1[7]);
      }
      if (t < FIN * TB) {        // stage x_t (with AR feedback)
        int s = t >> 5, f = t & 31;
        float xv;
        if (step >= SEQL && f < OUTD) xv = sout[s][f];
        else xv = x[((size_t)(b0 + s) * TOT + step) * FIN + f];
        sx[f][s] = xv;
      }
    }
    __syncthreads();

    // ================= C: layer-0 LSTM =================
    {
      float2 gI[2], gF[2], gG[2], gO[2];
      gI[0] = gI[1] = bg0[0]; gF[0] = gF[1] = bg0[1];
      gG[0] = gG[1] = bg0[2]; gO[0] = gO[1] = bg0[3];
      { // x part, K=32
        const float* row = Wih0 + u0;
#pragma unroll 4
        for (int k = 0; k < FIN; k++, row += G4) {
          const float2 wI = *(const float2*)(row);
          const float2 wF = *(const float2*)(row + HH);
          const float2 wG = *(const float2*)(row + 2 * HH);
          const float2 wO = *(const float2*)(row + 3 * HH);
          const float2 hv = *(const float2*)&sx[k][s2];
          GMAC2(gI, wI, hv); GMAC2(gF, wF, hv); GMAC2(gG, wG, hv); GMAC2(gO, wO, hv);
        }
      }
      { // recurrent, K=512, 1-deep weight prefetch
        const float* row = Whh0 + u0;
        float2 wI = *(const float2*)(row);
        float2 wF = *(const float2*)(row + HH);
        float2 wG = *(const float2*)(row + 2 * HH);
        float2 wO = *(const float2*)(row + 3 * HH);
        row += G4;
#pragma unroll 8
        for (int k = 0; k < HH - 1; k++, row += G4) {
          const float2 nI = *(const float2*)(row);
          const float2 nF = *(const float2*)(row + HH);
          const float2 nG = *(const float2*)(row + 2 * HH);
          const float2 nO = *(const float2*)(row + 3 * HH);
          const float2 hv = *(const float2*)&sh0[k][s2];
          GMAC2(gI, wI, hv); GMAC2(gF, wF, hv); GMAC2(gG, wG, hv); GMAC2(gO, wO, hv);
          wI = nI; wF = nF; wG = nG; wO = nO;
        }
        const float2 hv = *(const float2*)&sh0[HH - 1][s2];
        GMAC2(gI, wI, hv); GMAC2(gF, wF, hv); GMAC2(gG, wG, hv); GMAC2(gO, wO, hv);
      }
      const float2 cA = *(const float2*)&sc0[u0][s2];      // unit u0, 2 samples
      const float2 cB = *(const float2*)&sc0[u0 + 1][s2];  // unit u0+1
      float2 hA2, hB2, cA2, cB2;
      {
        float ig = sigf(gI[0].x), fg = sigf(gF[0].x);
        float gt = tanhf(gG[0].x), og = sigf(gO[0].x);
        float c2 = fmaf(fg, cA.x, ig * gt);
        cA2.x = c2; hA2.x = og * tanhf(c2);
        ig = sigf(gI[0].y); fg = sigf(gF[0].y);
        gt = tanhf(gG[0].y); og = sigf(gO[0].y);
        c2 = fmaf(fg, cB.x, ig * gt);
        cB2.x = c2; hB2.x = og * tanhf(c2);
        ig = sigf(gI[1].x); fg = sigf(gF[1].x);
        gt = tanhf(gG[1].x); og = sigf(gO[1].x);
        c2 = fmaf(fg, cA.y, ig * gt);
        cA2.y = c2; hA2.y = og * tanhf(c2);
        ig = sigf(gI[1].y); fg = sigf(gF[1].y);
        gt = tanhf(gG[1].y); og = sigf(gO[1].y);
        c2 = fmaf(fg, cB.y, ig * gt);
        cB2.y = c2; hB2.y = og * tanhf(c2);
      }
      __syncthreads();   // all K-loop reads of decoded sh0 done before overwrite
      *(float2*)&sh0[u0][s2]     = hA2;
      *(float2*)&sh0[u0 + 1][s2] = hB2;
      *(float2*)&sc0[u0][s2]     = cA2;
      *(float2*)&sc0[u0 + 1][s2] = cB2;
    }
    __syncthreads();

    // ================= D: layer-1 LSTM =================
    {
      float2 gI[2], gF[2], gG[2], gO[2];
      gI[0] = gI[1] = bg1[0]; gF[0] = gF[1] = bg1[1];
      gG[0] = gG[1] = bg1[2]; gO[0] = gO[1] = bg1[3];
      { // input = new h0, K=512, prefetch
        const float* row = Wih1 + u0;
        float2 wI = *(const float2*)(row);
        float2 wF = *(const float2*)(row + HH);
        float2 wG = *(const float2*)(row + 2 * HH);
        float2 wO = *(const float2*)(row + 3 * HH);
        row += G4;
#pragma unroll 8
        for (int k = 0; k < HH - 1; k++, row += G4) {
          const float2 nI = *(const float2*)(row);
          const float2 nF = *(const float2*)(row + HH);
          const float2 nG = *(const float2*)(row + 2 * HH);
          const float2 nO = *(const float2*)(row + 3 * HH);
          const float2 hv = *(const float2*)&sh0[k][s2];
          GMAC2(gI, wI, hv); GMAC2(gF, wF, hv); GMAC2(gG, wG, hv); GMAC2(gO, wO, hv);
          wI = nI; wF = nF; wG = nG; wO = nO;
        }
        const float2 hv = *(const float2*)&sh0[HH - 1][s2];
        GMAC2(gI, wI, hv); GMAC2(gF, wF, hv); GMAC2(gG, wG, hv); GMAC2(gO, wO, hv);
      }
      { // recurrent = decoded h1, K=512, prefetch
        const float* row = Whh1 + u0;
        float2 wI = *(const float2*)(row);
        float2 wF = *(const float2*)(row + HH);
        float2 wG = *(const float2*)(row + 2 * HH);
        float2 wO = *(const float2*)(row + 3 * HH);
        row += G4;
#pragma unroll 8
        for (int k = 0; k < HH - 1; k++, row += G4) {
          const float2 nI = *(const float2*)(row);
          const float2 nF = *(const float2*)(row + HH);
          const float2 nG = *(const float2*)(row + 2 * HH);
          const float2 nO = *(const float2*)(row + 3 * HH);
          const float2 hv = *(const float2*)&sh1[k][s2];
          GMAC2(gI, wI, hv); GMAC2(gF, wF, hv); GMAC2(gG, wG, hv); GMAC2(gO, wO, hv);
          wI = nI; wF = nF; wG = nG; wO = nO;
        }
        const float2 hv = *(const float2*)&sh1[HH - 1][s2];
        GMAC2(gI, wI, hv); GMAC2(gF, wF, hv); GMAC2(gG, wG, hv); GMAC2(gO, wO, hv);
      }
      const float2 cA = *(const float2*)&sc1[u0][s2];
      const float2 cB = *(const float2*)&sc1[u0 + 1][s2];
      float2 hA2, hB2, cA2, cB2;
      {
        float ig = sigf(gI[0].x), fg = sigf(gF[0].x);
        float gt = tanhf(gG[0].x), og = sigf(gO[0].x);
        float c2 = fmaf(fg, cA.x, ig * gt);
        cA2.x = c2; hA2.x = og * tanhf(c2);
        ig = sigf(gI[0].y); fg = sigf(gF[0].y);
        gt = tanhf(gG[0].y); og = sigf(gO[0].y);
        c2 = fmaf(fg, cB.x, ig * gt);
        cB2.x = c2; hB2.x = og * tanhf(c2);
        ig = sigf(gI[1].x); fg = sigf(gF[1].x);
        gt = tanhf(gG[1].x); og = sigf(gO[1].x);
        c2 = fmaf(fg, cA.y, ig * gt);
        cA2.y = c2; hA2.y = og * tanhf(c2);
        ig = sigf(gI[1].y); fg = sigf(gF[1].y);
        gt = tanhf(gG[1].y); og = sigf(gO[1].y);
        c2 = fmaf(fg, cB.y, ig * gt);
        cB2.y = c2; hB2.y = og * tanhf(c2);
      }
      __syncthreads();   // all K-loop reads of sh1 done before overwrite
      *(float2*)&sh1[u0][s2]     = hA2;
      *(float2*)&sh1[u0 + 1][s2] = hB2;
      *(float2*)&sc1[u0][s2]     = cA2;
      *(float2*)&sc1[u0 + 1][s2] = cB2;
    }

    // ================= E: final dense =================
    if (step >= SEQL - 1) {
      __syncthreads();  // new sh1 visible
      if (t < TB * OUTD) {
        int s = t >> 3, o = t & 7;
        float a = bf[o];
#pragma unroll 4
        for (int k = 0; k < HH; k++) a = fmaf(sh1[k][s], Wf[k * OUTD + o], a);
        sout[s][o] = a;
        int slot = step - (SEQL - 1);
        out[((size_t)(b0 + s) * (1 + LOOK) + slot) * OUTD + o] = a;
      }
    }
  }
}

extern "C" void kernel_launch(void* const* d_in, const int* in_sizes, int n_in,
                              void* d_out, int out_size, void* d_ws, size_t ws_size,
                              hipStream_t stream) {
  const float* x    = (const float*)d_in[0];
  const float* Wih0 = (const float*)d_in[1];
  const float* Whh0 = (const float*)d_in[2];
  const float* bih0 = (const float*)d_in[3];
  const float* bhh0 = (const float*)d_in[4];
  const float* Wih1 = (const float*)d_in[5];
  const float* Whh1 = (const float*)d_in[6];
  const float* bih1 = (const float*)d_in[7];
  const float* bhh1 = (const float*)d_in[8];
  const float* We   = (const float*)d_in[9];
  const float* be   = (const float*)d_in[10];
  const float* Wd   = (const float*)d_in[11];
  const float* bd   = (const float*)d_in[12];
  const float* Wf   = (const float*)d_in[13];
  const float* bf   = (const float*)d_in[14];

  fused_rnn<<<NB / TB, NTHR, 0, stream>>>(x, Wih0, Whh0, bih0, bhh0,
                                          Wih1, Whh1, bih1, bhh1,
                                          We, be, Wd, bd, Wf, bf,
                                          (float*)d_out);
}

// Round 8
// 80226.654 us; speedup vs baseline: 1.5923x; 1.5923x over previous
//
#include <hip/hip_runtime.h>
#include <hip/hip_bf16.h>
#include <math.h>

#define NB    2048
#define FIN   32
#define HH    512
#define G4    2048           // 4*H
#define BNE   64
#define OUTD  8
#define SEQL  128
#define LOOK  32
#define TOT   (SEQL + LOOK)
#define TB    8              // samples per workgroup
#define NTHR  1024

__device__ __forceinline__ float sigf(float v) { return 1.0f / (1.0f + expf(-v)); }

// acc[s] (float2) += state_s * w (float2)
#define MAC2(S, HS)                                    \
  {                                                    \
    a[S].x = fmaf(w.x, (HS), a[S].x);                  \
    a[S].y = fmaf(w.y, (HS), a[S].y);                  \
  }
#define MAC2x8()                                       \
  {                                                    \
    MAC2(0, hA.x); MAC2(1, hA.y); MAC2(2, hA.z); MAC2(3, hA.w); \
    MAC2(4, hB.x); MAC2(5, hB.y); MAC2(6, hB.z); MAC2(7, hB.w); \
  }

__global__ __launch_bounds__(NTHR)
void fused_rnn(const float* __restrict__ x,
               const float* __restrict__ Wih0, const float* __restrict__ Whh0,
               const float* __restrict__ bih0, const float* __restrict__ bhh0,
               const float* __restrict__ Wih1, const float* __restrict__ Whh1,
               const float* __restrict__ bih1, const float* __restrict__ bhh1,
               const float* __restrict__ We,   const float* __restrict__ be,
               const float* __restrict__ Wd,   const float* __restrict__ bd,
               const float* __restrict__ Wf,   const float* __restrict__ bf,
               float* __restrict__ out, int* __restrict__ ws)
{
  // states transposed [k][sample]: fixed-k access is a wave-uniform float4 broadcast
  __shared__ float sh0[HH][TB], sc0[HH][TB], sh1[HH][TB], sc1[HH][TB];  // 64 KB
  __shared__ float sg[TB][G4];       // gate pre-activations [sample][col], 64 KB
  __shared__ float sq[2][BNE][TB];   // trits [ae][j][sample], 4 KB
  __shared__ float sx[FIN][TB];      // staged x_t, transposed, 1 KB
  __shared__ float sout[TB][OUTD];   // last dense output (AR feedback)

  const int t  = threadIdx.x;          // 0..1023
  const int b0 = blockIdx.x * TB;      // first sample of this WG

  // per-XCD rendezvous counter (bid%8 = XCD under round-robin dispatch).
  // SOFT barrier: bounded spin + monotonic counter -> deadlock-impossible,
  // used only to phase-lock the 32 WGs of an XCD for L2 weight reuse.
  int* cnt = ws + (blockIdx.x & 7) * 32;

  for (int i = t; i < HH * TB; i += NTHR) {
    (&sh0[0][0])[i] = 0.f; (&sc0[0][0])[i] = 0.f;
    (&sh1[0][0])[i] = 0.f; (&sc1[0][0])[i] = 0.f;
  }

  // this thread owns gate cols (2t, 2t+1); bias = bih+bhh for those cols
  const float2 bb0 = make_float2(bih0[2*t]   + bhh0[2*t],
                                 bih0[2*t+1] + bhh0[2*t+1]);
  const float2 bb1 = make_float2(bih1[2*t]   + bhh1[2*t],
                                 bih1[2*t+1] + bhh1[2*t+1]);

  const double Athr = 0.5493061443340549;  // atanh(0.5): round(tanh(u)) threshold

  for (int step = 0; step < TOT; ++step) {
    // ---- per-XCD phase-lock (performance only; timeout => graceful de-sync) ----
    if (t == 0) {
      const int tgt = (step + 1) * 32;
      __hip_atomic_fetch_add(cnt, 1, __ATOMIC_RELAXED, __HIP_MEMORY_SCOPE_AGENT);
      int spins = 0;
      while (__hip_atomic_load(cnt, __ATOMIC_RELAXED, __HIP_MEMORY_SCOPE_AGENT) < tgt
             && spins < 4096) {
        __builtin_amdgcn_s_sleep(8);
        ++spins;
      }
    }
    __syncthreads();

    // ---------------- Phase A: encode both AEs (fp64, 1 bottleneck unit/thread) ----
    {
      const int ae = t >> 9, s = (t >> 6) & 7, n = t & 63;
      const float* Sh = ae ? &sh1[0][0] : &sh0[0][0];
      const float* Sc = ae ? &sc1[0][0] : &sc0[0][0];
      double a0 = (double)be[n];
      const float* we0 = We + n;
#pragma unroll 4
      for (int k = 0; k < HH; k++)
        a0 = fma((double)Sh[k * TB + s], (double)we0[(size_t)k * BNE], a0);
      const float* we1 = We + (size_t)HH * BNE + n;
#pragma unroll 4
      for (int k = 0; k < HH; k++)
        a0 = fma((double)Sc[k * TB + s], (double)we1[(size_t)k * BNE], a0);
      sq[ae][n][s] = (a0 > Athr) ? 1.f : ((a0 < -Athr) ? -1.f : 0.f);
    }
    __syncthreads();

    // ---------------- Phase B: decode both AEs (1 col/thread) -> states; stage x_t --
    {
      float aq0[TB], aq1[TB];
      const float bdv = bd[t];
#pragma unroll
      for (int s = 0; s < TB; s++) { aq0[s] = bdv; aq1[s] = bdv; }
      const float* wd = Wd + t;          // col t, row stride 1024
#pragma unroll 2
      for (int j = 0; j < BNE; j++) {
        const float w = wd[(size_t)j * (2 * HH)];
        const float4 qA0 = *(const float4*)&sq[0][j][0];
        const float4 qB0 = *(const float4*)&sq[0][j][4];
        const float4 qA1 = *(const float4*)&sq[1][j][0];
        const float4 qB1 = *(const float4*)&sq[1][j][4];
        aq0[0] = fmaf(qA0.x, w, aq0[0]); aq0[1] = fmaf(qA0.y, w, aq0[1]);
        aq0[2] = fmaf(qA0.z, w, aq0[2]); aq0[3] = fmaf(qA0.w, w, aq0[3]);
        aq0[4] = fmaf(qB0.x, w, aq0[4]); aq0[5] = fmaf(qB0.y, w, aq0[5]);
        aq0[6] = fmaf(qB0.z, w, aq0[6]); aq0[7] = fmaf(qB0.w, w, aq0[7]);
        aq1[0] = fmaf(qA1.x, w, aq1[0]); aq1[1] = fmaf(qA1.y, w, aq1[1]);
        aq1[2] = fmaf(qA1.z, w, aq1[2]); aq1[3] = fmaf(qA1.w, w, aq1[3]);
        aq1[4] = fmaf(qB1.x, w, aq1[4]); aq1[5] = fmaf(qB1.y, w, aq1[5]);
        aq1[6] = fmaf(qB1.z, w, aq1[6]); aq1[7] = fmaf(qB1.w, w, aq1[7]);
      }
      if (t < HH) {
#pragma unroll
        for (int s = 0; s < TB; s++) { sh0[t][s] = aq0[s]; sh1[t][s] = aq1[s]; }
      } else {
        const int c = t - HH;
#pragma unroll
        for (int s = 0; s < TB; s++) { sc0[c][s] = aq0[s]; sc1[c][s] = aq1[s]; }
      }
      if (t < FIN * TB) {   // 256 threads stage x_t (with AR feedback)
        int s = t >> 5, f = t & 31;
        float xv;
        if (step >= SEQL && f < OUTD) xv = sout[s][f];
        else xv = x[((size_t)(b0 + s) * TOT + step) * FIN + f];
        sx[f][s] = xv;
      }
    }
    __syncthreads();

    // ---------------- Phase C: layer-0 matmul (col pair/thread) ----------------
    {
      float2 a[TB];
#pragma unroll
      for (int s = 0; s < TB; s++) a[s] = bb0;
      const float2* wx = (const float2*)Wih0 + t;
#pragma unroll 4
      for (int k = 0; k < FIN; k++) {
        const float2 w  = wx[(size_t)k * (G4 / 2)];
        const float4 hA = *(const float4*)&sx[k][0];
        const float4 hB = *(const float4*)&sx[k][4];
        MAC2x8();
      }
      const float2* wh = (const float2*)Whh0 + t;
#pragma unroll 8
      for (int k = 0; k < HH; k++) {
        const float2 w  = wh[(size_t)k * (G4 / 2)];
        const float4 hA = *(const float4*)&sh0[k][0];
        const float4 hB = *(const float4*)&sh0[k][4];
        MAC2x8();
      }
#pragma unroll
      for (int s = 0; s < TB; s++) *(float2*)&sg[s][2 * t] = a[s];
    }
    __syncthreads();
    // layer-0 elementwise: unit h = t&511, 4 samples per thread
    {
      const int h  = t & (HH - 1);
      const int sb = (t >> 9) * 4;
#pragma unroll
      for (int s2 = 0; s2 < 4; s2++) {
        const int s = sb + s2;
        const float ig = sigf(sg[s][h]);
        const float fg = sigf(sg[s][HH + h]);
        const float gt = tanhf(sg[s][2 * HH + h]);
        const float og = sigf(sg[s][3 * HH + h]);
        const float c2 = fmaf(fg, sc0[h][s], ig * gt);
        sc0[h][s] = c2;
        sh0[h][s] = og * tanhf(c2);
      }
    }
    __syncthreads();

    // ---------------- Phase D: layer-1 matmul ----------------
    {
      float2 a[TB];
#pragma unroll
      for (int s = 0; s < TB; s++) a[s] = bb1;
      const float2* wx = (const float2*)Wih1 + t;
#pragma unroll 8
      for (int k = 0; k < HH; k++) {
        const float2 w  = wx[(size_t)k * (G4 / 2)];
        const float4 hA = *(const float4*)&sh0[k][0];   // new h0
        const float4 hB = *(const float4*)&sh0[k][4];
        MAC2x8();
      }
      const float2* wh = (const float2*)Whh1 + t;
#pragma unroll 8
      for (int k = 0; k < HH; k++) {
        const float2 w  = wh[(size_t)k * (G4 / 2)];
        const float4 hA = *(const float4*)&sh1[k][0];   // decoded h1
        const float4 hB = *(const float4*)&sh1[k][4];
        MAC2x8();
      }
#pragma unroll
      for (int s = 0; s < TB; s++) *(float2*)&sg[s][2 * t] = a[s];
    }
    __syncthreads();
    // layer-1 elementwise
    {
      const int h  = t & (HH - 1);
      const int sb = (t >> 9) * 4;
#pragma unroll
      for (int s2 = 0; s2 < 4; s2++) {
        const int s = sb + s2;
        const float ig = sigf(sg[s][h]);
        const float fg = sigf(sg[s][HH + h]);
        const float gt = tanhf(sg[s][2 * HH + h]);
        const float og = sigf(sg[s][3 * HH + h]);
        const float c2 = fmaf(fg, sc1[h][s], ig * gt);
        sc1[h][s] = c2;
        sh1[h][s] = og * tanhf(c2);
      }
    }

    // ---------------- Phase E: final dense (warm-up end + every AR step) ----------
    if (step >= SEQL - 1) {
      __syncthreads();  // new sh1 visible
      if (t < TB * OUTD) {
        int s = t >> 3, o = t & 7;
        float a = bf[o];
#pragma unroll 4
        for (int k = 0; k < HH; k++) a = fmaf(sh1[k][s], Wf[k * OUTD + o], a);
        sout[s][o] = a;
        int slot = step - (SEQL - 1);                 // 0..32
        out[((size_t)(b0 + s) * (1 + LOOK) + slot) * OUTD + o] = a;
      }
    }
  }
}

extern "C" void kernel_launch(void* const* d_in, const int* in_sizes, int n_in,
                              void* d_out, int out_size, void* d_ws, size_t ws_size,
                              hipStream_t stream) {
  const float* x    = (const float*)d_in[0];
  const float* Wih0 = (const float*)d_in[1];
  const float* Whh0 = (const float*)d_in[2];
  const float* bih0 = (const float*)d_in[3];
  const float* bhh0 = (const float*)d_in[4];
  const float* Wih1 = (const float*)d_in[5];
  const float* Whh1 = (const float*)d_in[6];
  const float* bih1 = (const float*)d_in[7];
  const float* bhh1 = (const float*)d_in[8];
  const float* We   = (const float*)d_in[9];
  const float* be   = (const float*)d_in[10];
  const float* Wd   = (const float*)d_in[11];
  const float* bd   = (const float*)d_in[12];
  const float* Wf   = (const float*)d_in[13];
  const float* bf   = (const float*)d_in[14];

  // zero the 8 XCD rendezvous counters (8*32 ints, padded) every launch
  hipMemsetAsync(d_ws, 0, 1024 * sizeof(int), stream);

  fused_rnn<<<NB / TB, NTHR, 0, stream>>>(x, Wih0, Whh0, bih0, bhh0,
                                          Wih1, Whh1, bih1, bhh1,
                                          We, be, Wd, bd, Wf, bf,
                                          (float*)d_out, (int*)d_ws);
}